// Round 9
// baseline (425.871 us; speedup 1.0000x reference)
//
#include <hip/hip_runtime.h>

// Problem constants (N=8192 rows, D=256 features)
#define NN 8192
#define DD 256
#define ND_ (NN * DD)

#define NEG_SLOPE 0.1f

typedef _Float16 half8 __attribute__((ext_vector_type(8)));
typedef _Float16 half4 __attribute__((ext_vector_type(4)));
typedef float f32x4 __attribute__((ext_vector_type(4)));
typedef float f32x16 __attribute__((ext_vector_type(16)));

__device__ __forceinline__ unsigned pkhalf2(_Float16 a, _Float16 b) {
    unsigned short ua = __builtin_bit_cast(unsigned short, a);
    unsigned short ub = __builtin_bit_cast(unsigned short, b);
    return (unsigned)ua | ((unsigned)ub << 16);
}

// ---------------------------------------------------------------------------
// prep_split: build transposed f16 hi/lo splits of u = h+d and v = h-d:
//   uT_hi/uT_lo/vT_hi/vT_lo : [DD=256 feature][NN=8192 node] f16  (plain)
// Tile 64 node x 64 feature via LDS transpose. Grid 128*4 = 512 blocks.
// ---------------------------------------------------------------------------
__global__ __launch_bounds__(256, 2)
void prep_split_kernel(const float* __restrict__ h, const float* __restrict__ d,
                       _Float16* __restrict__ uT_hi, _Float16* __restrict__ uT_lo,
                       _Float16* __restrict__ vT_hi, _Float16* __restrict__ vT_lo) {
    __shared__ float s_h[64 * 68];
    __shared__ float s_d[64 * 68];
    const int b  = blockIdx.x;
    const int kt = b >> 2;          // node-tile 0..127
    const int ct = b & 3;           // feature-tile 0..3
    const int k0 = kt * 64;
    const int c0 = ct * 64;
    const int t  = threadIdx.x;

#pragma unroll
    for (int e = 0; e < 4; ++e) {
        int idx = e * 256 + t;
        int r   = idx >> 4;                  // node 0..63
        int c4  = (idx & 15) << 2;           // feature 0..60
        float4 hv = *(const float4*)&h[(size_t)(k0 + r) * DD + c0 + c4];
        float4 dv = *(const float4*)&d[(size_t)(k0 + r) * DD + c0 + c4];
        *(float4*)&s_h[r * 68 + c4] = hv;
        *(float4*)&s_d[r * 68 + c4] = dv;
    }
    __syncthreads();

#pragma unroll
    for (int e = 0; e < 2; ++e) {
        int idx = e * 256 + t;
        int c   = idx >> 3;                  // feature-in-tile 0..63
        int seg = idx & 7;                   // node chunk of 8
        half8 uh, ul, vh, vl;
#pragma unroll
        for (int m = 0; m < 8; ++m) {
            float hh = s_h[(seg * 8 + m) * 68 + c];
            float dd = s_d[(seg * 8 + m) * 68 + c];
            float uu = hh + dd;
            float vv = hh - dd;
            _Float16 a = (_Float16)uu;
            uh[m] = a;
            ul[m] = (_Float16)(uu - (float)a);
            _Float16 bb = (_Float16)vv;
            vh[m] = bb;
            vl[m] = (_Float16)(vv - (float)bb);
        }
        size_t go = (size_t)(c0 + c) * NN + k0 + seg * 8;
        *(half8*)&uT_hi[go] = uh;
        *(half8*)&uT_lo[go] = ul;
        *(half8*)&vT_hi[go] = vh;
        *(half8*)&vT_lo[go] = vl;
    }
}

// ---------------------------------------------------------------------------
// agg_mfma: fp32-emulated-via-f16x3 MFMA (32x32x16) of split-K partials:
//   P = (A + A^T) @ u      Q = (A^T - A) @ v
// stored as f16 in Pbuf/Qbuf [2 halves][NN][DD].
//
// Block: 64 rows x 128 cols, 512 threads (8 waves): waves 0-3 P, 4-7 Q,
// each wave owns a 64x32 band (acc[2] of 32x32 frags).
// B-operand frags are read GLOBAL->REG directly (per-lane 16B contiguous in
// the transposed uT layout, L2/LLC-resident) -- no B LDS staging, no
// global_load_lds drain. LDS = s_a1 + S/D only = 29.7 KB -> 3-4 blocks/CU.
// Grid: 512 = 128 rb x 2 cb x 2 khalf (bit-swizzled as in R8).
// ---------------------------------------------------------------------------
__global__ __launch_bounds__(512, 6)
void agg_mfma_kernel(const float* __restrict__ alpha,
                     const _Float16* __restrict__ uT_hi, const _Float16* __restrict__ uT_lo,
                     const _Float16* __restrict__ vT_hi, const _Float16* __restrict__ vT_lo,
                     _Float16* __restrict__ Pbuf,   // [2][NN][DD]
                     _Float16* __restrict__ Qbuf) { // [2][NN][DD]
    // LDS carve (bytes):
    //  s_a1 : f32 [64][36]                               9216
    //  sS_hi/sS_lo/sD_hi/sD_lo : f16 [64 r][40 kpitch]   4*5120 = 20480
    __shared__ __align__(16) unsigned char smem[29696];
    float*    s_a1  = (float*)smem;
    _Float16* sS_hi = (_Float16*)(smem + 9216);
    _Float16* sS_lo = (_Float16*)(smem + 14336);
    _Float16* sD_hi = (_Float16*)(smem + 19456);
    _Float16* sD_lo = (_Float16*)(smem + 24576);

    const int raw   = blockIdx.x;
    const int khalf = raw & 1;
    const int cb    = (raw >> 3) & 1;
    const int rb    = ((raw >> 1) & 3) | ((raw >> 4) << 2);
    const int I0    = rb * 64;
    const int C0    = cb * 128;
    const int t     = threadIdx.x;
    const int w     = t >> 6;
    const int lane  = t & 63;

    const bool isP = (w < 4);
    const int  cw  = w & 3;                // 32-col band within the 128

    const _Float16* aHi = isP ? sS_hi : sD_hi;
    const _Float16* aLo = isP ? sS_lo : sD_lo;

    // per-lane B-frag global base: column c_glob, contiguous in k
    const int c_glob = C0 + cw * 32 + (lane & 31);
    const _Float16* bHg = (isP ? uT_hi : vT_hi) + (size_t)c_glob * NN + ((lane >> 5) << 3);
    const _Float16* bLg = (isP ? uT_lo : vT_lo) + (size_t)c_glob * NN + ((lane >> 5) << 3);

    f32x16 acc[2];
#pragma unroll
    for (int i = 0; i < 2; ++i)
#pragma unroll
        for (int r = 0; r < 16; ++r) acc[i][r] = 0.f;

    // staging / build / mfma index precompute
    const int r_a1  = t >> 3;              // 0..63
    const int k4a   = (t & 7) << 2;        // 0..28
    const int rbase = t & 15;              // build row base
    const int kp    = (t >> 4) & 15;       // build k-pair (kk = 2kp, 2kp+1)
    const int dup   = t >> 8;              // 0: rows +0/+16, 1: rows +32/+48
    const int lrow  = lane & 31;
    const int lk    = (lane >> 5) << 3;    // 0 or 8

    const int kbase = khalf * (NN / 2);

    for (int it = 0; it < 128; ++it) {
        const int k0g = kbase + it * 32;
        __syncthreads();   // barrier A: prev iter's s_a1/S/D reads complete

        // ---- alpha slabs -> regs, row slab -> s_a1 ----
        float4 pA1 = *(const float4*)&alpha[(size_t)(I0 + r_a1) * NN + k0g + k4a];
        float a2r[2][2];
#pragma unroll
        for (int jj = 0; jj < 2; ++jj)
#pragma unroll
            for (int e = 0; e < 2; ++e)
                a2r[jj][e] = alpha[(size_t)(k0g + 2 * kp + e) * NN +
                                   I0 + rbase + 16 * (dup * 2 + jj)];
        *(float4*)&s_a1[r_a1 * 36 + k4a] = pA1;
        __syncthreads();   // barrier B: s_a1 visible

        // ---- issue B-frag loads (global->reg, L2-resident); latency hides
        //      under the S/D build below ----
        half8 bH0 = *(const half8*)(bHg + k0g);
        half8 bH1 = *(const half8*)(bHg + k0g + 16);
        half8 bL0 = *(const half8*)(bLg + k0g);
        half8 bL1 = *(const half8*)(bLg + k0g + 16);

        // ---- build S = A^T+A, D = A^T-A  (f16 hi/lo, [row][k] pitch 40) ----
#pragma unroll
        for (int jj = 0; jj < 2; ++jj) {
            int row = rbase + 16 * (dup * 2 + jj);
            float2 tr = *(const float2*)&s_a1[row * 36 + 2 * kp];
            float s0 = a2r[jj][0] + tr.x, s1 = a2r[jj][1] + tr.y;
            float d0 = a2r[jj][0] - tr.x, d1 = a2r[jj][1] - tr.y;
            int adr = row * 20 + kp;       // u32 index (pitch 40 f16 = 20 u32)
            _Float16 sh0 = (_Float16)s0, sh1 = (_Float16)s1;
            ((unsigned*)sS_hi)[adr] = pkhalf2(sh0, sh1);
            ((unsigned*)sS_lo)[adr] =
                pkhalf2((_Float16)(s0 - (float)sh0), (_Float16)(s1 - (float)sh1));
            _Float16 dh0 = (_Float16)d0, dh1 = (_Float16)d1;
            ((unsigned*)sD_hi)[adr] = pkhalf2(dh0, dh1);
            ((unsigned*)sD_lo)[adr] =
                pkhalf2((_Float16)(d0 - (float)dh0), (_Float16)(d1 - (float)dh1));
        }
        __syncthreads();   // barrier C: S/D visible

        // ---- inner: 12 MFMA (32x32x16) per wave ----
        __builtin_amdgcn_s_setprio(1);
        {
            half8 aH0 = *(const half8*)&aHi[(lrow) * 40 + lk];
            half8 aH1 = *(const half8*)&aHi[(32 + lrow) * 40 + lk];
            half8 aL0 = *(const half8*)&aLo[(lrow) * 40 + lk];
            half8 aL1 = *(const half8*)&aLo[(32 + lrow) * 40 + lk];
            acc[0] = __builtin_amdgcn_mfma_f32_32x32x16_f16(aH0, bH0, acc[0], 0, 0, 0);
            acc[0] = __builtin_amdgcn_mfma_f32_32x32x16_f16(aH0, bL0, acc[0], 0, 0, 0);
            acc[0] = __builtin_amdgcn_mfma_f32_32x32x16_f16(aL0, bH0, acc[0], 0, 0, 0);
            acc[1] = __builtin_amdgcn_mfma_f32_32x32x16_f16(aH1, bH0, acc[1], 0, 0, 0);
            acc[1] = __builtin_amdgcn_mfma_f32_32x32x16_f16(aH1, bL0, acc[1], 0, 0, 0);
            acc[1] = __builtin_amdgcn_mfma_f32_32x32x16_f16(aL1, bH0, acc[1], 0, 0, 0);
        }
        {
            half8 aH0 = *(const half8*)&aHi[(lrow) * 40 + 16 + lk];
            half8 aH1 = *(const half8*)&aHi[(32 + lrow) * 40 + 16 + lk];
            half8 aL0 = *(const half8*)&aLo[(lrow) * 40 + 16 + lk];
            half8 aL1 = *(const half8*)&aLo[(32 + lrow) * 40 + 16 + lk];
            acc[0] = __builtin_amdgcn_mfma_f32_32x32x16_f16(aH0, bH1, acc[0], 0, 0, 0);
            acc[0] = __builtin_amdgcn_mfma_f32_32x32x16_f16(aH0, bL1, acc[0], 0, 0, 0);
            acc[0] = __builtin_amdgcn_mfma_f32_32x32x16_f16(aL0, bH1, acc[0], 0, 0, 0);
            acc[1] = __builtin_amdgcn_mfma_f32_32x32x16_f16(aH1, bH1, acc[1], 0, 0, 0);
            acc[1] = __builtin_amdgcn_mfma_f32_32x32x16_f16(aH1, bL1, acc[1], 0, 0, 0);
            acc[1] = __builtin_amdgcn_mfma_f32_32x32x16_f16(aL1, bH1, acc[1], 0, 0, 0);
        }
        __builtin_amdgcn_s_setprio(0);
    }

    // ---- epilogue: write f16 partials ----
    // C/D layout (32x32): col = lane&31, row = (reg&3) + 8*(reg>>2) + 4*(lane>>5)
    _Float16* dst = (isP ? Pbuf : Qbuf) + (size_t)khalf * ND_;
    const int colw = C0 + cw * 32 + (lane & 31);
#pragma unroll
    for (int rf = 0; rf < 2; ++rf)
#pragma unroll
        for (int reg = 0; reg < 16; ++reg) {
            int row = I0 + rf * 32 + (reg & 3) + ((reg >> 2) << 3) + ((lane >> 5) << 2);
            dst[(size_t)row * DD + colw] = (_Float16)acc[rf][reg];
        }
}

// ---------------------------------------------------------------------------
// stageB: combine P/Q partials into agg, then
//   out = leaky_relu( agg @ W1 + Y @ W2 )
// Block tile 64 x 128, 256 threads, 4x8 accum/thread, K=256 in BK=32 chunks.
// Grid 512: sel = b>>8 (0 = head output, 1 = dependent output).
// ---------------------------------------------------------------------------
__global__ __launch_bounds__(256, 2)
void stageB_kernel(const _Float16* __restrict__ Pbuf, const _Float16* __restrict__ Qbuf,
                   const float* __restrict__ head, const float* __restrict__ dep,
                   const float* __restrict__ alpha,
                   const float* __restrict__ Wah, const float* __restrict__ Wad,
                   const float* __restrict__ Wch, const float* __restrict__ Wcd,
                   float* __restrict__ out) {
    __shared__ float smem2[12544];
    __shared__ float s_dg[64];
    float* s_x  = smem2;            // [32][68] transposed X tile
    float* s_y  = smem2 + 2176;     // [32][68]
    float* s_w1 = smem2 + 4352;     // [32][128]
    float* s_w2 = smem2 + 8448;     // [32][128] -> 12544

    int b   = blockIdx.x;
    int sel = b >> 8;
    int rem = b & 255;
    int rb  = rem >> 1;
    int cb  = rem & 1;
    int I0  = rb * 64;
    int C0  = cb * 128;

    const float* Y  = sel ? dep : head;
    const float* W1 = sel ? Wad : Wah;
    const float* W2 = sel ? Wcd : Wch;
    float* dst = out + sel * ND_;

    int t  = threadIdx.x;
    int rg = t & 15, cg = t >> 4;
    int r0 = rg * 4, c0 = cg * 8;

    if (t < 64) s_dg[t] = alpha[(size_t)(I0 + t) * NN + I0 + t];

    float acc[4][8];
#pragma unroll
    for (int i = 0; i < 4; ++i)
#pragma unroll
        for (int j = 0; j < 8; ++j) acc[i][j] = 0.0f;

    for (int it = 0; it < 8; ++it) {
        int k0 = it * 32;
        __syncthreads();
#pragma unroll
        for (int e = 0; e < 2; ++e) {
            int idx = e * 256 + t;
            int r   = idx >> 3;              // 0..63
            int k4  = (idx & 7) << 2;        // 0..28
            size_t go = (size_t)(I0 + r) * DD + k0 + k4;
            half4 p0 = *(const half4*)&Pbuf[go];
            half4 p1 = *(const half4*)&Pbuf[ND_ + go];
            half4 q0 = *(const half4*)&Qbuf[go];
            half4 q1 = *(const half4*)&Qbuf[ND_ + go];
            float4 hv = *(const float4*)&head[go];
            float4 dv = *(const float4*)&dep[go];
            float dgv = s_dg[r];
            float hj[4] = {hv.x, hv.y, hv.z, hv.w};
            float dj[4] = {dv.x, dv.y, dv.z, dv.w};
#pragma unroll
            for (int j = 0; j < 4; ++j) {
                float Pv = (float)p0[j] + (float)p1[j];
                float Qv = (float)q0[j] + (float)q1[j];
                float uu = hj[j] + dj[j];
                float x  = (sel ? 0.5f * (Pv - Qv) : 0.5f * (Pv + Qv)) - dgv * uu;
                s_x[(k4 + j) * 68 + r] = x;
                s_y[(k4 + j) * 68 + r] = sel ? dj[j] : hj[j];
            }
        }
#pragma unroll
        for (int e = 0; e < 4; ++e) {
            int idx = e * 256 + t;
            int kkk = idx >> 5;
            int c4  = (idx & 31) << 2;
            *(float4*)&s_w1[kkk * 128 + c4] =
                *(const float4*)&W1[(size_t)(k0 + kkk) * DD + C0 + c4];
            *(float4*)&s_w2[kkk * 128 + c4] =
                *(const float4*)&W2[(size_t)(k0 + kkk) * DD + C0 + c4];
        }
        __syncthreads();
#pragma unroll 8
        for (int k = 0; k < 32; ++k) {
            float4 xv = *(const float4*)&s_x[k * 68 + r0];
            float4 yv = *(const float4*)&s_y[k * 68 + r0];
            float4 wa = *(const float4*)&s_w1[k * 128 + c0];
            float4 wb = *(const float4*)&s_w1[k * 128 + c0 + 4];
            float4 wc = *(const float4*)&s_w2[k * 128 + c0];
            float4 wd = *(const float4*)&s_w2[k * 128 + c0 + 4];
            float xs[4]  = {xv.x, xv.y, xv.z, xv.w};
            float ys[4]  = {yv.x, yv.y, yv.z, yv.w};
            float w1s[8] = {wa.x, wa.y, wa.z, wa.w, wb.x, wb.y, wb.z, wb.w};
            float w2s[8] = {wc.x, wc.y, wc.z, wc.w, wd.x, wd.y, wd.z, wd.w};
#pragma unroll
            for (int i = 0; i < 4; ++i)
#pragma unroll
                for (int j = 0; j < 8; ++j)
                    acc[i][j] += xs[i] * w1s[j] + ys[i] * w2s[j];
        }
    }

    // leaky relu + store
#pragma unroll
    for (int i = 0; i < 4; ++i) {
#pragma unroll
        for (int jv = 0; jv < 2; ++jv) {
            float4 o;
            float v0 = acc[i][4 * jv + 0];
            float v1 = acc[i][4 * jv + 1];
            float v2 = acc[i][4 * jv + 2];
            float v3 = acc[i][4 * jv + 3];
            o.x = v0 >= 0.0f ? v0 : NEG_SLOPE * v0;
            o.y = v1 >= 0.0f ? v1 : NEG_SLOPE * v1;
            o.z = v2 >= 0.0f ? v2 : NEG_SLOPE * v2;
            o.w = v3 >= 0.0f ? v3 : NEG_SLOPE * v3;
            *(float4*)&dst[(size_t)(I0 + r0 + i) * DD + C0 + c0 + 4 * jv] = o;
        }
    }
}

// ---------------------------------------------------------------------------
// kernel_launch
// workspace (_Float16 units): uT_hi[ND] uT_lo[ND] vT_hi[ND] vT_lo[ND]
//                             P[2*ND] Q[2*ND]  = 8*ND f16 = 32 MB
// ---------------------------------------------------------------------------
extern "C" void kernel_launch(void* const* d_in, const int* in_sizes, int n_in,
                              void* d_out, int out_size, void* d_ws, size_t ws_size,
                              hipStream_t stream) {
    const float* head  = (const float*)d_in[0];
    const float* dep   = (const float*)d_in[1];
    const float* alpha = (const float*)d_in[2];
    const float* Wah   = (const float*)d_in[3];
    const float* Wad   = (const float*)d_in[4];
    const float* Wch   = (const float*)d_in[5];
    const float* Wcd   = (const float*)d_in[6];
    float* out = (float*)d_out;

    _Float16* ws    = (_Float16*)d_ws;
    _Float16* uT_hi = ws;
    _Float16* uT_lo = ws + (size_t)ND_;
    _Float16* vT_hi = ws + (size_t)2 * ND_;
    _Float16* vT_lo = ws + (size_t)3 * ND_;
    _Float16* Pbuf  = ws + (size_t)4 * ND_;   // [2][NN][DD]
    _Float16* Qbuf  = ws + (size_t)6 * ND_;   // [2][NN][DD]

    prep_split_kernel<<<512, 256, 0, stream>>>(head, dep, uT_hi, uT_lo, vT_hi, vT_lo);
    agg_mfma_kernel<<<512, 512, 0, stream>>>(alpha, uT_hi, uT_lo, vT_hi, vT_lo, Pbuf, Qbuf);
    stageB_kernel<<<512, 256, 0, stream>>>(Pbuf, Qbuf, head, dep, alpha,
                                           Wah, Wad, Wch, Wcd, out);
}

// Round 10
// 384.242 us; speedup vs baseline: 1.1083x; 1.1083x over previous
//
#include <hip/hip_runtime.h>

// Problem constants (N=8192 rows, D=256 features)
#define NN 8192
#define DD 256
#define ND_ (NN * DD)

#define NEG_SLOPE 0.1f

typedef _Float16 half8 __attribute__((ext_vector_type(8)));
typedef _Float16 half4 __attribute__((ext_vector_type(4)));
typedef float f32x4 __attribute__((ext_vector_type(4)));
typedef float f32x16 __attribute__((ext_vector_type(16)));

// async global->LDS, 16B per lane; lds dst = wave-uniform base + lane*16
__device__ __forceinline__ void ld_g2l16(const void* g, void* l) {
    __builtin_amdgcn_global_load_lds(
        (const __attribute__((address_space(1))) void*)g,
        (__attribute__((address_space(3))) void*)l, 16, 0, 0);
}

__device__ __forceinline__ unsigned pkhalf2(_Float16 a, _Float16 b) {
    unsigned short ua = __builtin_bit_cast(unsigned short, a);
    unsigned short ub = __builtin_bit_cast(unsigned short, b);
    return (unsigned)ua | ((unsigned)ub << 16);
}

// producer-side LDS flush + barrier (no vmcnt drain!)
#define BARSYNC() asm volatile("s_waitcnt lgkmcnt(0)\n\ts_barrier" ::: "memory")

// ---------------------------------------------------------------------------
// prep_split: build f16 hi/lo splits of u = h+d, v = h-d in the SWIZZLED,
// k-block-tiled layout agg consumes via linear global_load_lds:
//   element (c, k):  kb = k>>5, gd = (k>>3)&3, slot = gd ^ ((c>>1)&3)
//   offset = kb*8192 + c*32 + slot*8 + (k&7)      (f16 units)
// Grid 128 node-tiles x 4 feature-tiles = 512 blocks, 256 threads.
// ---------------------------------------------------------------------------
__global__ __launch_bounds__(256, 2)
void prep_split_kernel(const float* __restrict__ h, const float* __restrict__ d,
                       _Float16* __restrict__ uS_hi, _Float16* __restrict__ uS_lo,
                       _Float16* __restrict__ vS_hi, _Float16* __restrict__ vS_lo) {
    __shared__ float s_h[64 * 68];
    __shared__ float s_d[64 * 68];
    const int b  = blockIdx.x;
    const int kt = b >> 2;          // node-tile 0..127 (64 nodes)
    const int ct = b & 3;           // feature-tile 0..3 (64 features)
    const int k0 = kt * 64;
    const int c0 = ct * 64;
    const int t  = threadIdx.x;

#pragma unroll
    for (int e = 0; e < 4; ++e) {
        int idx = e * 256 + t;
        int r   = idx >> 4;                  // node 0..63
        int c4  = (idx & 15) << 2;           // feature 0..60
        float4 hv = *(const float4*)&h[(size_t)(k0 + r) * DD + c0 + c4];
        float4 dv = *(const float4*)&d[(size_t)(k0 + r) * DD + c0 + c4];
        *(float4*)&s_h[r * 68 + c4] = hv;
        *(float4*)&s_d[r * 68 + c4] = dv;
    }
    __syncthreads();

#pragma unroll
    for (int e = 0; e < 2; ++e) {
        int idx = e * 256 + t;
        int c   = idx >> 3;                  // feature-in-tile 0..63
        int seg = idx & 7;                   // node chunk of 8 (k' = seg*8)
        half8 uh, ul, vh, vl;
#pragma unroll
        for (int m = 0; m < 8; ++m) {
            float hh = s_h[(seg * 8 + m) * 68 + c];
            float dd = s_d[(seg * 8 + m) * 68 + c];
            float uu = hh + dd;
            float vv = hh - dd;
            _Float16 a = (_Float16)uu;
            uh[m] = a;
            ul[m] = (_Float16)(uu - (float)a);
            _Float16 bb = (_Float16)vv;
            vh[m] = bb;
            vl[m] = (_Float16)(vv - (float)bb);
        }
        int    cg   = c0 + c;
        int    kb   = kt * 2 + (seg >> 2);
        int    slot = (seg & 3) ^ ((cg >> 1) & 3);
        size_t go   = (size_t)kb * 8192 + (size_t)cg * 32 + slot * 8;
        *(half8*)&uS_hi[go] = uh;
        *(half8*)&uS_lo[go] = ul;
        *(half8*)&vS_hi[go] = vh;
        *(half8*)&vS_lo[go] = vl;
    }
}

// ---------------------------------------------------------------------------
// agg_mfma: fp32-emulated-via-f16x3 MFMA (32x32x16) of split-K partials:
//   P = (A + A^T) @ u      Q = (A^T - A) @ v
// stored as f16 in Pbuf/Qbuf [2 halves][NN][DD].
//
// Software-pipelined with RAW s_barrier + counted waits (no vmcnt(0) drain):
//   P0: ds_write s_a1(it) [prefetched]          ; lgkm0+barrier (beta)
//   P1: issue gl_lds B(it); sched_barrier;
//       issue alpha slabs(it+1) -> regs; build S/D(it) ; lgkm0+barrier (gamma)
//   P2: vmcnt(5) [B landed, slabs(it+1) stay in flight]; 12 MFMA
// Block 64r x 128c, 512 thr (8 waves: 0-3 P, 4-7 Q), 2 blocks/CU.
// Grid: 512 = 128 rb x 2 cb x 2 khalf (bit-swizzled).
// ---------------------------------------------------------------------------
__global__ __launch_bounds__(512, 4)
void agg_mfma_kernel(const float* __restrict__ alpha,
                     const _Float16* __restrict__ uS_hi, const _Float16* __restrict__ uS_lo,
                     const _Float16* __restrict__ vS_hi, const _Float16* __restrict__ vS_lo,
                     _Float16* __restrict__ Pbuf,   // [2][NN][DD]
                     _Float16* __restrict__ Qbuf) { // [2][NN][DD]
    // LDS carve (bytes):
    //  s_a1 : f32 [64][36]                               9216
    //  sS_hi/sS_lo/sD_hi/sD_lo : f16 [64 r][40 kpitch]   4*5120 = 20480
    //  sB0..sB3 : f16 [128 c][32 k] linear (swizzled)    4*8192 = 32768
    __shared__ __align__(16) unsigned char smem[62464];
    float*    s_a1  = (float*)smem;
    _Float16* sS_hi = (_Float16*)(smem + 9216);
    _Float16* sS_lo = (_Float16*)(smem + 14336);
    _Float16* sD_hi = (_Float16*)(smem + 19456);
    _Float16* sD_lo = (_Float16*)(smem + 24576);
    _Float16* sB0   = (_Float16*)(smem + 29696);
    _Float16* sB1   = (_Float16*)(smem + 37888);
    _Float16* sB2   = (_Float16*)(smem + 46080);
    _Float16* sB3   = (_Float16*)(smem + 54272);

    const int raw   = blockIdx.x;
    const int khalf = raw & 1;
    const int cb    = (raw >> 3) & 1;
    const int rb    = ((raw >> 1) & 3) | ((raw >> 4) << 2);
    const int I0    = rb * 64;
    const int C0    = cb * 128;
    const int t     = threadIdx.x;
    const int w     = t >> 6;
    const int lane  = t & 63;

    const bool isP = (w < 4);
    const int  cw  = w & 3;                // 32-col band within the 128

    const _Float16* aHi = isP ? sS_hi : sD_hi;
    const _Float16* aLo = isP ? sS_lo : sD_lo;
    const _Float16* bHi = isP ? sB0 : sB2;
    const _Float16* bLo = isP ? sB1 : sB3;

    const _Float16* gA[4] = {uS_hi, uS_lo, vS_hi, vS_lo};
    _Float16* sBp[4] = {sB0, sB1, sB2, sB3};

    f32x16 acc[2];
#pragma unroll
    for (int i = 0; i < 2; ++i)
#pragma unroll
        for (int r = 0; r < 16; ++r) acc[i][r] = 0.f;

    // staging / build / mfma index precompute
    const int r_a1  = t >> 3;              // 0..63
    const int k4a   = (t & 7) << 2;        // 0..28
    const int rbase = t & 15;              // build row base
    const int kp    = (t >> 4) & 15;       // build k-pair (kk = 2kp, 2kp+1)
    const int dup   = t >> 8;              // 0: rows +0/+16, 1: rows +32/+48
    const int lrow  = lane & 31;
    const int lk    = (lane >> 5) << 3;    // 0 or 8

    const int kbase = khalf * (NN / 2);
    const int c_local = cw * 32 + lrow;

    // ---- prologue: prefetch alpha slabs for it=0 ----
    float4 pA1 = *(const float4*)&alpha[(size_t)(I0 + r_a1) * NN + kbase + k4a];
    float  a2r00, a2r01, a2r10, a2r11;
    a2r00 = alpha[(size_t)(kbase + 2 * kp + 0) * NN + I0 + rbase + 16 * (dup * 2 + 0)];
    a2r01 = alpha[(size_t)(kbase + 2 * kp + 1) * NN + I0 + rbase + 16 * (dup * 2 + 0)];
    a2r10 = alpha[(size_t)(kbase + 2 * kp + 0) * NN + I0 + rbase + 16 * (dup * 2 + 1)];
    a2r11 = alpha[(size_t)(kbase + 2 * kp + 1) * NN + I0 + rbase + 16 * (dup * 2 + 1)];

    for (int it = 0; it < 128; ++it) {
        const int kb = khalf * 128 + it;

        // ---- P0: write prefetched alpha row-slab to s_a1 ----
        *(float4*)&s_a1[r_a1 * 36 + k4a] = pA1;
        BARSYNC();   // beta: prev MFMA's LDS reads retired everywhere + s_a1 visible

        // ---- P1a: issue B-tile gl_lds (Bbuf free since beta) ----
        {
            size_t gbase = (size_t)kb * 8192 + cb * 4096 + (size_t)(w * 512 + lane * 8);
#pragma unroll
            for (int arr = 0; arr < 4; ++arr)
                ld_g2l16(gA[arr] + gbase, (unsigned char*)sBp[arr] + w * 1024);
        }
        __builtin_amdgcn_sched_barrier(0);   // pin order: gl_lds BEFORE next-slab loads

        // ---- P1b: issue alpha slabs for it+1 (clamped; in flight through MFMA) ----
        const int itn  = (it < 127) ? it + 1 : 127;
        const int k0gn = kbase + itn * 32;
        float4 pA1n = *(const float4*)&alpha[(size_t)(I0 + r_a1) * NN + k0gn + k4a];
        float a2rn00 = alpha[(size_t)(k0gn + 2 * kp + 0) * NN + I0 + rbase + 16 * (dup * 2 + 0)];
        float a2rn01 = alpha[(size_t)(k0gn + 2 * kp + 1) * NN + I0 + rbase + 16 * (dup * 2 + 0)];
        float a2rn10 = alpha[(size_t)(k0gn + 2 * kp + 0) * NN + I0 + rbase + 16 * (dup * 2 + 1)];
        float a2rn11 = alpha[(size_t)(k0gn + 2 * kp + 1) * NN + I0 + rbase + 16 * (dup * 2 + 1)];

        // ---- P1c: build S = A^T+A, D = A^T-A (f16 hi/lo, [row][k] pitch 40) ----
        {
            int row = rbase + 16 * (dup * 2 + 0);
            float2 tr = *(const float2*)&s_a1[row * 36 + 2 * kp];
            float s0 = a2r00 + tr.x, s1 = a2r01 + tr.y;
            float d0 = a2r00 - tr.x, d1 = a2r01 - tr.y;
            int adr = row * 20 + kp;
            _Float16 sh0 = (_Float16)s0, sh1 = (_Float16)s1;
            ((unsigned*)sS_hi)[adr] = pkhalf2(sh0, sh1);
            ((unsigned*)sS_lo)[adr] =
                pkhalf2((_Float16)(s0 - (float)sh0), (_Float16)(s1 - (float)sh1));
            _Float16 dh0 = (_Float16)d0, dh1 = (_Float16)d1;
            ((unsigned*)sD_hi)[adr] = pkhalf2(dh0, dh1);
            ((unsigned*)sD_lo)[adr] =
                pkhalf2((_Float16)(d0 - (float)dh0), (_Float16)(d1 - (float)dh1));
        }
        {
            int row = rbase + 16 * (dup * 2 + 1);
            float2 tr = *(const float2*)&s_a1[row * 36 + 2 * kp];
            float s0 = a2r10 + tr.x, s1 = a2r11 + tr.y;
            float d0 = a2r10 - tr.x, d1 = a2r11 - tr.y;
            int adr = row * 20 + kp;
            _Float16 sh0 = (_Float16)s0, sh1 = (_Float16)s1;
            ((unsigned*)sS_hi)[adr] = pkhalf2(sh0, sh1);
            ((unsigned*)sS_lo)[adr] =
                pkhalf2((_Float16)(s0 - (float)sh0), (_Float16)(s1 - (float)sh1));
            _Float16 dh0 = (_Float16)d0, dh1 = (_Float16)d1;
            ((unsigned*)sD_hi)[adr] = pkhalf2(dh0, dh1);
            ((unsigned*)sD_lo)[adr] =
                pkhalf2((_Float16)(d0 - (float)dh0), (_Float16)(d1 - (float)dh1));
        }
        BARSYNC();   // gamma: S/D visible

        // ---- P2: wait B tiles (counted! slabs it+1 stay in flight), MFMA ----
        asm volatile("s_waitcnt vmcnt(5)" ::: "memory");
        __builtin_amdgcn_sched_barrier(0);
        __builtin_amdgcn_s_setprio(1);
#pragma unroll
        for (int s = 0; s < 2; ++s) {
            half8 aH0 = *(const half8*)&aHi[(lrow) * 40 + s * 16 + lk];
            half8 aH1 = *(const half8*)&aHi[(32 + lrow) * 40 + s * 16 + lk];
            half8 aL0 = *(const half8*)&aLo[(lrow) * 40 + s * 16 + lk];
            half8 aL1 = *(const half8*)&aLo[(32 + lrow) * 40 + s * 16 + lk];
            int gd = s * 2 + (lane >> 5);
            int sl = gd ^ ((c_local >> 1) & 3);
            int bi = c_local * 32 + sl * 8;
            half8 bH = *(const half8*)&bHi[bi];
            half8 bL = *(const half8*)&bLo[bi];
            acc[0] = __builtin_amdgcn_mfma_f32_32x32x16_f16(aH0, bH, acc[0], 0, 0, 0);
            acc[0] = __builtin_amdgcn_mfma_f32_32x32x16_f16(aH0, bL, acc[0], 0, 0, 0);
            acc[0] = __builtin_amdgcn_mfma_f32_32x32x16_f16(aL0, bH, acc[0], 0, 0, 0);
            acc[1] = __builtin_amdgcn_mfma_f32_32x32x16_f16(aH1, bH, acc[1], 0, 0, 0);
            acc[1] = __builtin_amdgcn_mfma_f32_32x32x16_f16(aH1, bL, acc[1], 0, 0, 0);
            acc[1] = __builtin_amdgcn_mfma_f32_32x32x16_f16(aL1, bH, acc[1], 0, 0, 0);
        }
        __builtin_amdgcn_s_setprio(0);

        // rotate prefetched slabs
        pA1 = pA1n;
        a2r00 = a2rn00; a2r01 = a2rn01; a2r10 = a2rn10; a2r11 = a2rn11;
    }

    // ---- epilogue: write f16 partials ----
    // C/D layout (32x32): col = lane&31, row = (reg&3) + 8*(reg>>2) + 4*(lane>>5)
    _Float16* dst = (isP ? Pbuf : Qbuf) + (size_t)khalf * ND_;
    const int colw = C0 + cw * 32 + (lane & 31);
#pragma unroll
    for (int rf = 0; rf < 2; ++rf)
#pragma unroll
        for (int reg = 0; reg < 16; ++reg) {
            int row = I0 + rf * 32 + (reg & 3) + ((reg >> 2) << 3) + ((lane >> 5) << 2);
            dst[(size_t)row * DD + colw] = (_Float16)acc[rf][reg];
        }
}

// ---------------------------------------------------------------------------
// stageB: combine P/Q partials into agg, then
//   out = leaky_relu( agg @ W1 + Y @ W2 )
// Block tile 64 x 128, 256 threads, 4x8 accum/thread, K=256 in BK=32 chunks.
// Grid 512: sel = b>>8 (0 = head output, 1 = dependent output).
// ---------------------------------------------------------------------------
__global__ __launch_bounds__(256, 2)
void stageB_kernel(const _Float16* __restrict__ Pbuf, const _Float16* __restrict__ Qbuf,
                   const float* __restrict__ head, const float* __restrict__ dep,
                   const float* __restrict__ alpha,
                   const float* __restrict__ Wah, const float* __restrict__ Wad,
                   const float* __restrict__ Wch, const float* __restrict__ Wcd,
                   float* __restrict__ out) {
    __shared__ float smem2[12544];
    __shared__ float s_dg[64];
    float* s_x  = smem2;            // [32][68] transposed X tile
    float* s_y  = smem2 + 2176;     // [32][68]
    float* s_w1 = smem2 + 4352;     // [32][128]
    float* s_w2 = smem2 + 8448;     // [32][128] -> 12544

    int b   = blockIdx.x;
    int sel = b >> 8;
    int rem = b & 255;
    int rb  = rem >> 1;
    int cb  = rem & 1;
    int I0  = rb * 64;
    int C0  = cb * 128;

    const float* Y  = sel ? dep : head;
    const float* W1 = sel ? Wad : Wah;
    const float* W2 = sel ? Wcd : Wch;
    float* dst = out + sel * ND_;

    int t  = threadIdx.x;
    int rg = t & 15, cg = t >> 4;
    int r0 = rg * 4, c0 = cg * 8;

    if (t < 64) s_dg[t] = alpha[(size_t)(I0 + t) * NN + I0 + t];

    float acc[4][8];
#pragma unroll
    for (int i = 0; i < 4; ++i)
#pragma unroll
        for (int j = 0; j < 8; ++j) acc[i][j] = 0.0f;

    for (int it = 0; it < 8; ++it) {
        int k0 = it * 32;
        __syncthreads();
#pragma unroll
        for (int e = 0; e < 2; ++e) {
            int idx = e * 256 + t;
            int r   = idx >> 3;              // 0..63
            int k4  = (idx & 7) << 2;        // 0..28
            size_t go = (size_t)(I0 + r) * DD + k0 + k4;
            half4 p0 = *(const half4*)&Pbuf[go];
            half4 p1 = *(const half4*)&Pbuf[ND_ + go];
            half4 q0 = *(const half4*)&Qbuf[go];
            half4 q1 = *(const half4*)&Qbuf[ND_ + go];
            float4 hv = *(const float4*)&head[go];
            float4 dv = *(const float4*)&dep[go];
            float dgv = s_dg[r];
            float hj[4] = {hv.x, hv.y, hv.z, hv.w};
            float dj[4] = {dv.x, dv.y, dv.z, dv.w};
#pragma unroll
            for (int j = 0; j < 4; ++j) {
                float Pv = (float)p0[j] + (float)p1[j];
                float Qv = (float)q0[j] + (float)q1[j];
                float uu = hj[j] + dj[j];
                float x  = (sel ? 0.5f * (Pv - Qv) : 0.5f * (Pv + Qv)) - dgv * uu;
                s_x[(k4 + j) * 68 + r] = x;
                s_y[(k4 + j) * 68 + r] = sel ? dj[j] : hj[j];
            }
        }
#pragma unroll
        for (int e = 0; e < 4; ++e) {
            int idx = e * 256 + t;
            int kkk = idx >> 5;
            int c4  = (idx & 31) << 2;
            *(float4*)&s_w1[kkk * 128 + c4] =
                *(const float4*)&W1[(size_t)(k0 + kkk) * DD + C0 + c4];
            *(float4*)&s_w2[kkk * 128 + c4] =
                *(const float4*)&W2[(size_t)(k0 + kkk) * DD + C0 + c4];
        }
        __syncthreads();
#pragma unroll 8
        for (int k = 0; k < 32; ++k) {
            float4 xv = *(const float4*)&s_x[k * 68 + r0];
            float4 yv = *(const float4*)&s_y[k * 68 + r0];
            float4 wa = *(const float4*)&s_w1[k * 128 + c0];
            float4 wb = *(const float4*)&s_w1[k * 128 + c0 + 4];
            float4 wc = *(const float4*)&s_w2[k * 128 + c0];
            float4 wd = *(const float4*)&s_w2[k * 128 + c0 + 4];
            float xs[4]  = {xv.x, xv.y, xv.z, xv.w};
            float ys[4]  = {yv.x, yv.y, yv.z, yv.w};
            float w1s[8] = {wa.x, wa.y, wa.z, wa.w, wb.x, wb.y, wb.z, wb.w};
            float w2s[8] = {wc.x, wc.y, wc.z, wc.w, wd.x, wd.y, wd.z, wd.w};
#pragma unroll
            for (int i = 0; i < 4; ++i)
#pragma unroll
                for (int j = 0; j < 8; ++j)
                    acc[i][j] += xs[i] * w1s[j] + ys[i] * w2s[j];
        }
    }

    // leaky relu + store
#pragma unroll
    for (int i = 0; i < 4; ++i) {
#pragma unroll
        for (int jv = 0; jv < 2; ++jv) {
            float4 o;
            float v0 = acc[i][4 * jv + 0];
            float v1 = acc[i][4 * jv + 1];
            float v2 = acc[i][4 * jv + 2];
            float v3 = acc[i][4 * jv + 3];
            o.x = v0 >= 0.0f ? v0 : NEG_SLOPE * v0;
            o.y = v1 >= 0.0f ? v1 : NEG_SLOPE * v1;
            o.z = v2 >= 0.0f ? v2 : NEG_SLOPE * v2;
            o.w = v3 >= 0.0f ? v3 : NEG_SLOPE * v3;
            *(float4*)&dst[(size_t)(I0 + r0 + i) * DD + C0 + c0 + 4 * jv] = o;
        }
    }
}

// ---------------------------------------------------------------------------
// kernel_launch
// workspace (_Float16 units): uS_hi[ND] uS_lo[ND] vS_hi[ND] vS_lo[ND]
//                             P[2*ND] Q[2*ND]  = 8*ND f16 = 32 MB
// ---------------------------------------------------------------------------
extern "C" void kernel_launch(void* const* d_in, const int* in_sizes, int n_in,
                              void* d_out, int out_size, void* d_ws, size_t ws_size,
                              hipStream_t stream) {
    const float* head  = (const float*)d_in[0];
    const float* dep   = (const float*)d_in[1];
    const float* alpha = (const float*)d_in[2];
    const float* Wah   = (const float*)d_in[3];
    const float* Wad   = (const float*)d_in[4];
    const float* Wch   = (const float*)d_in[5];
    const float* Wcd   = (const float*)d_in[6];
    float* out = (float*)d_out;

    _Float16* ws    = (_Float16*)d_ws;
    _Float16* uS_hi = ws;
    _Float16* uS_lo = ws + (size_t)ND_;
    _Float16* vS_hi = ws + (size_t)2 * ND_;
    _Float16* vS_lo = ws + (size_t)3 * ND_;
    _Float16* Pbuf  = ws + (size_t)4 * ND_;   // [2][NN][DD]
    _Float16* Qbuf  = ws + (size_t)6 * ND_;   // [2][NN][DD]

    prep_split_kernel<<<512, 256, 0, stream>>>(head, dep, uS_hi, uS_lo, vS_hi, vS_lo);
    agg_mfma_kernel<<<512, 512, 0, stream>>>(alpha, uS_hi, uS_lo, vS_hi, vS_lo, Pbuf, Qbuf);
    stageB_kernel<<<512, 256, 0, stream>>>(Pbuf, Qbuf, head, dep, alpha,
                                           Wah, Wad, Wch, Wcd, out);
}

// Round 12
// 297.295 us; speedup vs baseline: 1.4325x; 1.2925x over previous
//
#include <hip/hip_runtime.h>

// Problem constants (N=8192 rows, D=256 features)
#define NN 8192
#define DD 256
#define ND_ (NN * DD)

#define NEG_SLOPE 0.1f

typedef _Float16 half8 __attribute__((ext_vector_type(8)));
typedef _Float16 half4 __attribute__((ext_vector_type(4)));
typedef float f32x4 __attribute__((ext_vector_type(4)));
typedef float f32x16 __attribute__((ext_vector_type(16)));

// async global->LDS, 16B per lane; lds dst = wave-uniform base + lane*16
__device__ __forceinline__ void ld_g2l16(const void* g, void* l) {
    __builtin_amdgcn_global_load_lds(
        (const __attribute__((address_space(1))) void*)g,
        (__attribute__((address_space(3))) void*)l, 16, 0, 0);
}

__device__ __forceinline__ unsigned pkhalf2(_Float16 a, _Float16 b) {
    unsigned short ua = __builtin_bit_cast(unsigned short, a);
    unsigned short ub = __builtin_bit_cast(unsigned short, b);
    return (unsigned)ua | ((unsigned)ub << 16);
}

// ---------------------------------------------------------------------------
// prep_split: f16 (hi-only) u = h+d, v = h-d in the SWIZZLED k-block layout
// agg consumes via linear global_load_lds:
//   element (c, k):  kb = k>>5, gd = (k>>3)&3, slot = gd ^ ((c>>1)&3)
//   offset = kb*8192 + c*32 + slot*8 + (k&7)      (f16 units)
// Grid 128 node-tiles x 4 feature-tiles = 512 blocks, 256 threads.
// ---------------------------------------------------------------------------
__global__ __launch_bounds__(256, 2)
void prep_split_kernel(const float* __restrict__ h, const float* __restrict__ d,
                       _Float16* __restrict__ uS_hi, _Float16* __restrict__ vS_hi) {
    __shared__ float s_h[64 * 68];
    __shared__ float s_d[64 * 68];
    const int b  = blockIdx.x;
    const int kt = b >> 2;          // node-tile 0..127 (64 nodes)
    const int ct = b & 3;           // feature-tile 0..3 (64 features)
    const int k0 = kt * 64;
    const int c0 = ct * 64;
    const int t  = threadIdx.x;

#pragma unroll
    for (int e = 0; e < 4; ++e) {
        int idx = e * 256 + t;
        int r   = idx >> 4;                  // node 0..63
        int c4  = (idx & 15) << 2;           // feature 0..60
        float4 hv = *(const float4*)&h[(size_t)(k0 + r) * DD + c0 + c4];
        float4 dv = *(const float4*)&d[(size_t)(k0 + r) * DD + c0 + c4];
        *(float4*)&s_h[r * 68 + c4] = hv;
        *(float4*)&s_d[r * 68 + c4] = dv;
    }
    __syncthreads();

#pragma unroll
    for (int e = 0; e < 2; ++e) {
        int idx = e * 256 + t;
        int c   = idx >> 3;                  // feature-in-tile 0..63
        int seg = idx & 7;                   // node chunk of 8 (k' = seg*8)
        half8 uh, vh;
#pragma unroll
        for (int m = 0; m < 8; ++m) {
            float hh = s_h[(seg * 8 + m) * 68 + c];
            float dd = s_d[(seg * 8 + m) * 68 + c];
            uh[m] = (_Float16)(hh + dd);
            vh[m] = (_Float16)(hh - dd);
        }
        int    cg   = c0 + c;
        int    kb   = kt * 2 + (seg >> 2);
        int    slot = (seg & 3) ^ ((cg >> 1) & 3);
        size_t go   = (size_t)kb * 8192 + (size_t)cg * 32 + slot * 8;
        *(half8*)&uS_hi[go] = uh;
        *(half8*)&vS_hi[go] = vh;
    }
}

// ---------------------------------------------------------------------------
// agg_mfma: f16x1 MFMA (32x32x16) split-K partials:
//   P = (A + A^T) @ u      Q = (A^T - A) @ v       (hi terms only)
// stored as f16 in Pbuf/Qbuf [2 halves][NN][DD].
//
// Two 32-wide k-subblocks per barrier pair (BK=64 effective, 64 iters).
// Race-fixed protocol: each wave waits OWN gl_lds (counted vmcnt) + flushes
// ds_writes (lgkmcnt 0) BEFORE s_barrier; barrier publishes all writes.
// Block 64r x 128c, 512 thr (8 waves: 0-3 P, 4-7 Q), LDS 52KB -> 2 blk/CU.
// Grid: 512 = 128 rb x 2 cb x 2 khalf (bit-swizzled).
// ---------------------------------------------------------------------------
__global__ __launch_bounds__(512, 4)
void agg_mfma_kernel(const float* __restrict__ alpha,
                     const _Float16* __restrict__ uS_hi, const _Float16* __restrict__ vS_hi,
                     _Float16* __restrict__ Pbuf,   // [2][NN][DD]
                     _Float16* __restrict__ Qbuf) { // [2][NN][DD]
    // LDS carve (bytes):
    //  sS0/sD0/sS1/sD1 : f16 [64 r][40 kpitch]   4*5120 = 20480
    //  sBu0/sBv0/sBu1/sBv1 : f16 [128c][32k]     4*8192 = 32768  -> 53248
    __shared__ __align__(16) unsigned char smem[53248];
    _Float16* sS0  = (_Float16*)smem;
    _Float16* sD0  = (_Float16*)(smem + 5120);
    _Float16* sS1  = (_Float16*)(smem + 10240);
    _Float16* sD1  = (_Float16*)(smem + 15360);
    _Float16* sBu0 = (_Float16*)(smem + 20480);
    _Float16* sBv0 = (_Float16*)(smem + 28672);
    _Float16* sBu1 = (_Float16*)(smem + 36864);
    _Float16* sBv1 = (_Float16*)(smem + 45056);

    const int raw   = blockIdx.x;
    const int khalf = raw & 1;
    const int cb    = (raw >> 3) & 1;
    const int rb    = ((raw >> 1) & 3) | ((raw >> 4) << 2);
    const int I0    = rb * 64;
    const int C0    = cb * 128;
    const int t     = threadIdx.x;
    const int w     = t >> 6;
    const int lane  = t & 63;

    const bool isP = (w < 4);
    const int  cw  = w & 3;                // 32-col band within the 128

    const _Float16* aP0 = isP ? sS0 : sD0;
    const _Float16* aP1 = isP ? sS1 : sD1;
    const _Float16* b0  = isP ? sBu0 : sBv0;
    const _Float16* b1  = isP ? sBu1 : sBv1;

    f32x16 acc0, acc1;
#pragma unroll
    for (int r = 0; r < 16; ++r) { acc0[r] = 0.f; acc1[r] = 0.f; }

    // build / mfma index precompute
    const int rbase = t & 15;
    const int kp    = (t >> 4) & 15;       // k-pair within sub: k = 2kp, 2kp+1
    const int dup   = t >> 8;              // 0 or 1 (wave-uniform)
    const int row0  = rbase + 32 * dup;    // rows row0, row0+16
    const int lrow  = lane & 31;
    const int lk    = (lane >> 5) << 3;    // 0 or 8
    const int kbase = khalf * (NN / 2);
    const int c_local = cw * 32 + lrow;

    // ---- prologue: issue alpha(it=0) loads (12: 8 scalar col + 4 float2 row) ----
    float a0_00, a0_01, a0_10, a0_11, a1_00, a1_01, a1_10, a1_11;
    float2 ar0_0, ar1_0, ar0_1, ar1_1;
    {
        const int kk0 = kbase + 2 * kp;
        size_t c0off = (size_t)kk0 * NN + I0;
        a0_00 = alpha[c0off + row0];
        a0_01 = alpha[c0off + NN + row0];
        a0_10 = alpha[c0off + row0 + 16];
        a0_11 = alpha[c0off + NN + row0 + 16];
        ar0_0 = *(const float2*)&alpha[(size_t)(I0 + row0) * NN + kk0];
        ar1_0 = *(const float2*)&alpha[(size_t)(I0 + row0 + 16) * NN + kk0];
        size_t c1off = c0off + (size_t)32 * NN;
        a1_00 = alpha[c1off + row0];
        a1_01 = alpha[c1off + NN + row0];
        a1_10 = alpha[c1off + row0 + 16];
        a1_11 = alpha[c1off + NN + row0 + 16];
        ar0_1 = *(const float2*)&alpha[(size_t)(I0 + row0) * NN + kk0 + 32];
        ar1_1 = *(const float2*)&alpha[(size_t)(I0 + row0 + 16) * NN + kk0 + 32];
    }

    for (int it = 0; it < 64; ++it) {
        // ---- (1) alpha(it) arrived (only thing in flight at loop top) ----
        asm volatile("s_waitcnt vmcnt(0)" ::: "memory");
        __builtin_amdgcn_sched_barrier(0);

        // ---- (2) build S/D f16 pairs in regs (both subs) ----
        unsigned su0_0 = pkhalf2((_Float16)(a0_00 + ar0_0.x), (_Float16)(a0_01 + ar0_0.y));
        unsigned du0_0 = pkhalf2((_Float16)(a0_00 - ar0_0.x), (_Float16)(a0_01 - ar0_0.y));
        unsigned su1_0 = pkhalf2((_Float16)(a0_10 + ar1_0.x), (_Float16)(a0_11 + ar1_0.y));
        unsigned du1_0 = pkhalf2((_Float16)(a0_10 - ar1_0.x), (_Float16)(a0_11 - ar1_0.y));
        unsigned su0_1 = pkhalf2((_Float16)(a1_00 + ar0_1.x), (_Float16)(a1_01 + ar0_1.y));
        unsigned du0_1 = pkhalf2((_Float16)(a1_00 - ar0_1.x), (_Float16)(a1_01 - ar0_1.y));
        unsigned su1_1 = pkhalf2((_Float16)(a1_10 + ar1_1.x), (_Float16)(a1_11 + ar1_1.y));
        unsigned du1_1 = pkhalf2((_Float16)(a1_10 - ar1_1.x), (_Float16)(a1_11 - ar1_1.y));

        // ---- (3) barrier: all waves done READING it-1's LDS (drain-free) ----
        __syncthreads();

        // ---- (4) ds_write S/D (pitch 40 f16 = 20 u32/row) ----
        ((unsigned*)sS0)[row0 * 20 + kp]        = su0_0;
        ((unsigned*)sS0)[(row0 + 16) * 20 + kp] = su1_0;
        ((unsigned*)sD0)[row0 * 20 + kp]        = du0_0;
        ((unsigned*)sD0)[(row0 + 16) * 20 + kp] = du1_0;
        ((unsigned*)sS1)[row0 * 20 + kp]        = su0_1;
        ((unsigned*)sS1)[(row0 + 16) * 20 + kp] = su1_1;
        ((unsigned*)sD1)[row0 * 20 + kp]        = du0_1;
        ((unsigned*)sD1)[(row0 + 16) * 20 + kp] = du1_1;

        // ---- (5) issue B-tile gl_lds (4; sB free since barrier (3)) ----
        {
            size_t gb0 = (size_t)(khalf * 128 + it * 2) * 8192 + cb * 4096 +
                         (size_t)(w * 512 + lane * 8);
            ld_g2l16(uS_hi + gb0, (unsigned char*)sBu0 + w * 1024);
            ld_g2l16(vS_hi + gb0, (unsigned char*)sBv0 + w * 1024);
            ld_g2l16(uS_hi + gb0 + 8192, (unsigned char*)sBu1 + w * 1024);
            ld_g2l16(vS_hi + gb0 + 8192, (unsigned char*)sBv1 + w * 1024);
        }
        __builtin_amdgcn_sched_barrier(0);   // pin: gl_lds BEFORE alpha loads

        // ---- (6) issue alpha(it+1) loads (12; stay in flight through MFMA) ----
        const int itn = (it + 1) & 63;
        float b0_00, b0_01, b0_10, b0_11, b1_00, b1_01, b1_10, b1_11;
        float2 br0_0, br1_0, br0_1, br1_1;
        {
            const int kk0 = kbase + itn * 64 + 2 * kp;
            size_t c0off = (size_t)kk0 * NN + I0;
            b0_00 = alpha[c0off + row0];
            b0_01 = alpha[c0off + NN + row0];
            b0_10 = alpha[c0off + row0 + 16];
            b0_11 = alpha[c0off + NN + row0 + 16];
            br0_0 = *(const float2*)&alpha[(size_t)(I0 + row0) * NN + kk0];
            br1_0 = *(const float2*)&alpha[(size_t)(I0 + row0 + 16) * NN + kk0];
            size_t c1off = c0off + (size_t)32 * NN;
            b1_00 = alpha[c1off + row0];
            b1_01 = alpha[c1off + NN + row0];
            b1_10 = alpha[c1off + row0 + 16];
            b1_11 = alpha[c1off + NN + row0 + 16];
            br0_1 = *(const float2*)&alpha[(size_t)(I0 + row0) * NN + kk0 + 32];
            br1_1 = *(const float2*)&alpha[(size_t)(I0 + row0 + 16) * NN + kk0 + 32];
        }
        __builtin_amdgcn_sched_barrier(0);

        // ---- (7) RACE-FIX ORDER: own gl_lds done + ds_writes flushed,
        //          THEN barrier publishes all waves' writes ----
        asm volatile("s_waitcnt vmcnt(8)" ::: "memory");   // >=8 alpha always in flight
        asm volatile("s_waitcnt lgkmcnt(0)" ::: "memory");
        __builtin_amdgcn_s_barrier();
        __builtin_amdgcn_sched_barrier(0);

        // ---- (8) 8 MFMA (32x32x16), f16x1 ----
        __builtin_amdgcn_s_setprio(1);
#pragma unroll
        for (int s = 0; s < 2; ++s) {
            int gd = s * 2 + (lane >> 5);
            int sl = gd ^ ((c_local >> 1) & 3);
            int bi = c_local * 32 + sl * 8;
            half8 aH0 = *(const half8*)&aP0[(lrow) * 40 + s * 16 + lk];
            half8 aH1 = *(const half8*)&aP0[(32 + lrow) * 40 + s * 16 + lk];
            half8 bH  = *(const half8*)&b0[bi];
            acc0 = __builtin_amdgcn_mfma_f32_32x32x16_f16(aH0, bH, acc0, 0, 0, 0);
            acc1 = __builtin_amdgcn_mfma_f32_32x32x16_f16(aH1, bH, acc1, 0, 0, 0);
        }
#pragma unroll
        for (int s = 0; s < 2; ++s) {
            int gd = s * 2 + (lane >> 5);
            int sl = gd ^ ((c_local >> 1) & 3);
            int bi = c_local * 32 + sl * 8;
            half8 aH0 = *(const half8*)&aP1[(lrow) * 40 + s * 16 + lk];
            half8 aH1 = *(const half8*)&aP1[(32 + lrow) * 40 + s * 16 + lk];
            half8 bH  = *(const half8*)&b1[bi];
            acc0 = __builtin_amdgcn_mfma_f32_32x32x16_f16(aH0, bH, acc0, 0, 0, 0);
            acc1 = __builtin_amdgcn_mfma_f32_32x32x16_f16(aH1, bH, acc1, 0, 0, 0);
        }
        __builtin_amdgcn_s_setprio(0);

        // rotate prefetched alpha
        a0_00 = b0_00; a0_01 = b0_01; a0_10 = b0_10; a0_11 = b0_11;
        a1_00 = b1_00; a1_01 = b1_01; a1_10 = b1_10; a1_11 = b1_11;
        ar0_0 = br0_0; ar1_0 = br1_0; ar0_1 = br0_1; ar1_1 = br1_1;
    }

    // ---- epilogue: write f16 partials ----
    // C/D layout (32x32): col = lane&31, row = (reg&3) + 8*(reg>>2) + 4*(lane>>5)
    _Float16* dst = (isP ? Pbuf : Qbuf) + (size_t)khalf * ND_;
    const int colw = C0 + cw * 32 + (lane & 31);
#pragma unroll
    for (int reg = 0; reg < 16; ++reg) {
        int rr = (reg & 3) + ((reg >> 2) << 3) + ((lane >> 5) << 2);
        dst[(size_t)(I0 + rr) * DD + colw]      = (_Float16)acc0[reg];
        dst[(size_t)(I0 + 32 + rr) * DD + colw] = (_Float16)acc1[reg];
    }
}

// ---------------------------------------------------------------------------
// stageB: combine P/Q partials into agg, then
//   out = leaky_relu( agg @ W1 + Y @ W2 )
// Block tile 64 x 128, 256 threads, 4x8 accum/thread, K=256 in BK=32 chunks.
// Grid 512: sel = b>>8 (0 = head output, 1 = dependent output).
// ---------------------------------------------------------------------------
__global__ __launch_bounds__(256, 2)
void stageB_kernel(const _Float16* __restrict__ Pbuf, const _Float16* __restrict__ Qbuf,
                   const float* __restrict__ head, const float* __restrict__ dep,
                   const float* __restrict__ alpha,
                   const float* __restrict__ Wah, const float* __restrict__ Wad,
                   const float* __restrict__ Wch, const float* __restrict__ Wcd,
                   float* __restrict__ out) {
    __shared__ float smem2[12544];
    __shared__ float s_dg[64];
    float* s_x  = smem2;            // [32][68] transposed X tile
    float* s_y  = smem2 + 2176;     // [32][68]
    float* s_w1 = smem2 + 4352;     // [32][128]
    float* s_w2 = smem2 + 8448;     // [32][128] -> 12544

    int b   = blockIdx.x;
    int sel = b >> 8;
    int rem = b & 255;
    int rb  = rem >> 1;
    int cb  = rem & 1;
    int I0  = rb * 64;
    int C0  = cb * 128;

    const float* Y  = sel ? dep : head;
    const float* W1 = sel ? Wad : Wah;
    const float* W2 = sel ? Wcd : Wch;
    float* dst = out + sel * ND_;

    int t  = threadIdx.x;
    int rg = t & 15, cg = t >> 4;
    int r0 = rg * 4, c0 = cg * 8;

    if (t < 64) s_dg[t] = alpha[(size_t)(I0 + t) * NN + I0 + t];

    float acc[4][8];
#pragma unroll
    for (int i = 0; i < 4; ++i)
#pragma unroll
        for (int j = 0; j < 8; ++j) acc[i][j] = 0.0f;

    for (int it = 0; it < 8; ++it) {
        int k0 = it * 32;
        __syncthreads();
#pragma unroll
        for (int e = 0; e < 2; ++e) {
            int idx = e * 256 + t;
            int r   = idx >> 3;              // 0..63
            int k4  = (idx & 7) << 2;        // 0..28
            size_t go = (size_t)(I0 + r) * DD + k0 + k4;
            half4 p0 = *(const half4*)&Pbuf[go];
            half4 p1 = *(const half4*)&Pbuf[ND_ + go];
            half4 q0 = *(const half4*)&Qbuf[go];
            half4 q1 = *(const half4*)&Qbuf[ND_ + go];
            float4 hv = *(const float4*)&head[go];
            float4 dv = *(const float4*)&dep[go];
            float dgv = s_dg[r];
            float hj[4] = {hv.x, hv.y, hv.z, hv.w};
            float dj[4] = {dv.x, dv.y, dv.z, dv.w};
#pragma unroll
            for (int j = 0; j < 4; ++j) {
                float Pv = (float)p0[j] + (float)p1[j];
                float Qv = (float)q0[j] + (float)q1[j];
                float uu = hj[j] + dj[j];
                float x  = (sel ? 0.5f * (Pv - Qv) : 0.5f * (Pv + Qv)) - dgv * uu;
                s_x[(k4 + j) * 68 + r] = x;
                s_y[(k4 + j) * 68 + r] = sel ? dj[j] : hj[j];
            }
        }
#pragma unroll
        for (int e = 0; e < 4; ++e) {
            int idx = e * 256 + t;
            int kkk = idx >> 5;
            int c4  = (idx & 31) << 2;
            *(float4*)&s_w1[kkk * 128 + c4] =
                *(const float4*)&W1[(size_t)(k0 + kkk) * DD + C0 + c4];
            *(float4*)&s_w2[kkk * 128 + c4] =
                *(const float4*)&W2[(size_t)(k0 + kkk) * DD + C0 + c4];
        }
        __syncthreads();
#pragma unroll 8
        for (int k = 0; k < 32; ++k) {
            float4 xv = *(const float4*)&s_x[k * 68 + r0];
            float4 yv = *(const float4*)&s_y[k * 68 + r0];
            float4 wa = *(const float4*)&s_w1[k * 128 + c0];
            float4 wb = *(const float4*)&s_w1[k * 128 + c0 + 4];
            float4 wc = *(const float4*)&s_w2[k * 128 + c0];
            float4 wd = *(const float4*)&s_w2[k * 128 + c0 + 4];
            float xs[4]  = {xv.x, xv.y, xv.z, xv.w};
            float ys[4]  = {yv.x, yv.y, yv.z, yv.w};
            float w1s[8] = {wa.x, wa.y, wa.z, wa.w, wb.x, wb.y, wb.z, wb.w};
            float w2s[8] = {wc.x, wc.y, wc.z, wc.w, wd.x, wd.y, wd.z, wd.w};
#pragma unroll
            for (int i = 0; i < 4; ++i)
#pragma unroll
                for (int j = 0; j < 8; ++j)
                    acc[i][j] += xs[i] * w1s[j] + ys[i] * w2s[j];
        }
    }

    // leaky relu + store
#pragma unroll
    for (int i = 0; i < 4; ++i) {
#pragma unroll
        for (int jv = 0; jv < 2; ++jv) {
            float4 o;
            float v0 = acc[i][4 * jv + 0];
            float v1 = acc[i][4 * jv + 1];
            float v2 = acc[i][4 * jv + 2];
            float v3 = acc[i][4 * jv + 3];
            o.x = v0 >= 0.0f ? v0 : NEG_SLOPE * v0;
            o.y = v1 >= 0.0f ? v1 : NEG_SLOPE * v1;
            o.z = v2 >= 0.0f ? v2 : NEG_SLOPE * v2;
            o.w = v3 >= 0.0f ? v3 : NEG_SLOPE * v3;
            *(float4*)&dst[(size_t)(I0 + r0 + i) * DD + C0 + c0 + 4 * jv] = o;
        }
    }
}

// ---------------------------------------------------------------------------
// kernel_launch
// workspace (_Float16 units): uS_hi[ND] vS_hi[ND] P[2*ND] Q[2*ND] = 24 MB
// ---------------------------------------------------------------------------
extern "C" void kernel_launch(void* const* d_in, const int* in_sizes, int n_in,
                              void* d_out, int out_size, void* d_ws, size_t ws_size,
                              hipStream_t stream) {
    const float* head  = (const float*)d_in[0];
    const float* dep   = (const float*)d_in[1];
    const float* alpha = (const float*)d_in[2];
    const float* Wah   = (const float*)d_in[3];
    const float* Wad   = (const float*)d_in[4];
    const float* Wch   = (const float*)d_in[5];
    const float* Wcd   = (const float*)d_in[6];
    float* out = (float*)d_out;

    _Float16* ws    = (_Float16*)d_ws;
    _Float16* uS_hi = ws;
    _Float16* vS_hi = ws + (size_t)ND_;
    _Float16* Pbuf  = ws + (size_t)2 * ND_;   // [2][NN][DD]
    _Float16* Qbuf  = ws + (size_t)4 * ND_;   // [2][NN][DD]

    prep_split_kernel<<<512, 256, 0, stream>>>(head, dep, uS_hi, vS_hi);
    agg_mfma_kernel<<<512, 512, 0, stream>>>(alpha, uS_hi, vS_hi, Pbuf, Qbuf);
    stageB_kernel<<<512, 256, 0, stream>>>(Pbuf, Qbuf, head, dep, alpha,
                                           Wah, Wad, Wch, Wcd, out);
}